// Round 6
// baseline (135.596 us; speedup 1.0000x reference)
//
#include <hip/hip_runtime.h>
#include <hip/hip_bf16.h>
#include <stdint.h>

// FP8QDQLinear: out[m,o] = 4 * (q_in @ q_w^T) + bias, q_* exact e4m3 values.
// R6: rebalance R5's 8-phase to 2 phases per K-tile (LDS-read was over-
// subscribed: 32 b128/wave/K-tile vs 24 minimum; 8 barriers/K-tile).
// Phase X: READ_A(mh0)+READ_B(all 4 frags, kept in regs) | stage A(k+1) | BAR
//          | 16 MFMA | BAR.
// Phase Y: READ_A(mh1) | stage B(k+1) | BAR | 16 MFMA | vmcnt(0) | BAR.
// MX-scaled fp8 16x16x128, unit E8M0 scales = exact e4m3 math.
// LDS column-chunk layout (slot = col16*256 + row), conflict-free (verified 0).

typedef __attribute__((ext_vector_type(4))) float f32x4;
typedef __attribute__((ext_vector_type(2))) int i32x2;
typedef __attribute__((ext_vector_type(4))) int i32x4;
typedef __attribute__((ext_vector_type(8))) int i32x8;

#define FP8_MAX 448.0f
#define UNIT_SCALE 0x7F7F7F7F  // E8M0 127 = 2^0 in every byte

// ---------------- quantization pass: f32 -> e4m3fn bytes ----------------
__global__ void quant_fp8_kernel(const float* __restrict__ x,
                                 uint32_t* __restrict__ q,
                                 float mul, int n8) {
    int i = blockIdx.x * blockDim.x + threadIdx.x;
    if (i >= n8) return;
    const float4* xv = (const float4*)x;
    float4 v0 = xv[2 * i];
    float4 v1 = xv[2 * i + 1];
    float a[8] = {v0.x, v0.y, v0.z, v0.w, v1.x, v1.y, v1.z, v1.w};
#pragma unroll
    for (int j = 0; j < 8; ++j) {
        float t = a[j] * mul;
        t = fminf(fmaxf(t, -FP8_MAX), FP8_MAX);
        a[j] = t;
    }
    int lo = 0, hi = 0;
    lo = __builtin_amdgcn_cvt_pk_fp8_f32(a[0], a[1], lo, false);
    lo = __builtin_amdgcn_cvt_pk_fp8_f32(a[2], a[3], lo, true);
    hi = __builtin_amdgcn_cvt_pk_fp8_f32(a[4], a[5], hi, false);
    hi = __builtin_amdgcn_cvt_pk_fp8_f32(a[6], a[7], hi, true);
    i32x2 out;
    out.x = lo;
    out.y = hi;
    ((i32x2*)q)[i] = out;
}

// ---------------- MX-fp8 GEMM: C = 4*(A_q @ W_q^T) + bias ----------------
#define KTILES 32  // K / 128

__device__ static inline void gload_lds16(const void* g, void* l) {
    __builtin_amdgcn_global_load_lds(
        (const __attribute__((address_space(1))) void*)g,
        (__attribute__((address_space(3))) void*)l, 16, 0, 0);
}

// stage a full 32 KB operand K-tile: 4 calls x (512 thr x 16B)
#define STAGE_FULL(GSRC, KB, LBASE)                                        \
    gload_lds16((GSRC) + (KB),       (LBASE) + t * 16);                    \
    gload_lds16((GSRC) + (KB) + 32,  (LBASE) + 8192  + t * 16);            \
    gload_lds16((GSRC) + (KB) + 64,  (LBASE) + 16384 + t * 16);            \
    gload_lds16((GSRC) + (KB) + 96,  (LBASE) + 24576 + t * 16);

#define READ_A(LBASE, MH)                                                  \
    _Pragma("unroll") for (int m = 0; m < 4; ++m) {                        \
        i32x4 lo = *(const i32x4*)((LBASE) + aoff + (MH) * 1024 + m * 256);       \
        i32x4 hi = *(const i32x4*)((LBASE) + aoff + (MH) * 1024 + m * 256 + 4096);\
        areg[m] = (i32x8){lo[0], lo[1], lo[2], lo[3], hi[0], hi[1], hi[2], hi[3]};\
    }

#define READ_B_ALL(LBASE)                                                  \
    _Pragma("unroll") for (int n = 0; n < 4; ++n) {                        \
        i32x4 lo = *(const i32x4*)((LBASE) + boff + n * 256);                     \
        i32x4 hi = *(const i32x4*)((LBASE) + boff + n * 256 + 4096);              \
        breg[n] = (i32x8){lo[0], lo[1], lo[2], lo[3], hi[0], hi[1], hi[2], hi[3]};\
    }

#define MFMA16(MH)                                                         \
    __builtin_amdgcn_s_setprio(1);                                         \
    _Pragma("unroll") for (int m = 0; m < 4; ++m)                          \
        _Pragma("unroll") for (int n = 0; n < 4; ++n)                      \
            acc[(MH) * 4 + m][n] =                                         \
                __builtin_amdgcn_mfma_scale_f32_16x16x128_f8f6f4(          \
                    areg[m], breg[n], acc[(MH) * 4 + m][n],                \
                    0, 0, 0, UNIT_SCALE, 0, UNIT_SCALE);                   \
    __builtin_amdgcn_s_setprio(0);

#define BAR() __builtin_amdgcn_s_barrier()
#define VM0() asm volatile("s_waitcnt vmcnt(0)" ::: "memory")

__global__ __launch_bounds__(512, 2) void fp8_gemm_bias_kernel(
        const uint8_t* __restrict__ Aq, const uint8_t* __restrict__ Wq,
        const float* __restrict__ bias, float* __restrict__ C,
        int M, int N, int K) {
    __shared__ __align__(16) uint8_t lds[131072];
    uint8_t* const sA0 = lds;           // buf0 A (even K-tiles)
    uint8_t* const sB0 = lds + 32768;   // buf0 B
    uint8_t* const sA1 = lds + 65536;   // buf1 A (odd K-tiles)
    uint8_t* const sB1 = lds + 98304;   // buf1 B

    const int t = threadIdx.x;
    const int lane = t & 63;
    const int w = t >> 6;       // wave 0..7
    const int wr = w >> 2;      // wave row 0..1  (128 rows each)
    const int wc = w & 3;       // wave col 0..3  (64 cols each)
    const int lr = lane & 15;
    const int lk = lane >> 4;   // K-group (32 bytes)

    // XCD-aware swizzle: 256 blocks, 8 XCDs, 32 per XCD
    const int bid = blockIdx.x;
    const int swz = (bid & 7) * 32 + (bid >> 3);
    const int bm = swz >> 4;
    const int bn = swz & 15;

    const uint8_t* Abase = Aq + (size_t)(bm * 256) * K;
    const uint8_t* Bbase = Wq + (size_t)(bn * 256) * K;

    // staging source: call for col-pair c: row = t&255, col16 = 2c + (t>>8)
    const int srow = t & 255;
    const int scol = (t >> 8) * 16;
    const uint8_t* gA = Abase + (size_t)srow * K + scol;
    const uint8_t* gB = Bbase + (size_t)srow * K + scol;

    // fragment read bases: A row = wr*128 + mh*64 + m*16 + lr, cols (2lk,2lk+1)
    const int aoff = lk * 8192 + wr * 2048 + lr * 16;
    const int boff = lk * 8192 + wc * 1024 + lr * 16;

    f32x4 acc[8][4];
#pragma unroll
    for (int mi = 0; mi < 8; ++mi)
#pragma unroll
        for (int ni = 0; ni < 4; ++ni)
            acc[mi][ni] = (f32x4){0.f, 0.f, 0.f, 0.f};

    i32x8 areg[4], breg[4];

    // ---- prologue: K-tile 0 -> buf0, drain, barrier ----
    STAGE_FULL(gA, 0, sA0)
    STAGE_FULL(gB, 0, sB0)
    VM0();
    BAR();

    for (int it = 0; it < KTILES / 2; ++it) {
        const int kb1 = (2 * it + 1) * 128;         // odd K-tile -> buf1
        const int kb2 = ((2 * it + 2) & 31) * 128;  // next even  -> buf0

        // ---- K-tile 2it (buf0) ----
        // X0
        READ_A(sA0, 0)
        READ_B_ALL(sB0)
        STAGE_FULL(gA, kb1, sA1)
        BAR();
        MFMA16(0)
        BAR();
        // Y0
        READ_A(sA0, 1)
        STAGE_FULL(gB, kb1, sB1)
        BAR();
        MFMA16(1)
        VM0();   // A(k+1)+B(k+1) complete; all waves' by post-BAR
        BAR();

        // ---- K-tile 2it+1 (buf1) ----
        // X1
        READ_A(sA1, 0)
        READ_B_ALL(sB1)
        STAGE_FULL(gA, kb2, sA0)
        BAR();
        MFMA16(0)
        BAR();
        // Y1
        READ_A(sA1, 1)
        STAGE_FULL(gB, kb2, sB0)
        BAR();
        MFMA16(1)
        VM0();
        BAR();
    }

    // ---- epilogue: C/D layout col=lane&15, row=(lane>>4)*4+j ----
    const int crow0 = bm * 256 + wr * 128 + lk * 4;
    const int ccol0 = bn * 256 + wc * 64 + lr;
#pragma unroll
    for (int ni = 0; ni < 4; ++ni) {
        const int col = ccol0 + ni * 16;
        const float bv = bias[col];
#pragma unroll
        for (int mi = 0; mi < 8; ++mi) {
            const int row = crow0 + mi * 16;
#pragma unroll
            for (int j = 0; j < 4; ++j) {
                C[(size_t)(row + j) * N + col] = acc[mi][ni][j] * 4.0f + bv;
            }
        }
    }
}

extern "C" void kernel_launch(void* const* d_in, const int* in_sizes, int n_in,
                              void* d_out, int out_size, void* d_ws, size_t ws_size,
                              hipStream_t stream) {
    const int M = 4096, N = 4096, K = 4096;
    const float* input  = (const float*)d_in[0];   // [M][K] f32
    const float* weight = (const float*)d_in[1];   // [N][K] f32 (e4m3-grid values)
    const float* bias   = (const float*)d_in[2];   // [N] f32
    float* out = (float*)d_out;                    // [M][N] f32

    uint8_t* Aq = (uint8_t*)d_ws;                        // 16 MiB
    uint8_t* Wq = (uint8_t*)d_ws + (size_t)M * K;        // 16 MiB

    {
        int n8 = (M * K) / 8;
        int blocks = (n8 + 255) / 256;
        quant_fp8_kernel<<<blocks, 256, 0, stream>>>(input, (uint32_t*)Aq, 0.5f, n8);
        quant_fp8_kernel<<<blocks, 256, 0, stream>>>(weight, (uint32_t*)Wq, 1.0f, n8);
    }

    dim3 grid(256);  // (M/256) x (N/256), XCD-swizzled in-kernel
    fp8_gemm_bias_kernel<<<grid, 512, 0, stream>>>(Aq, Wq, bias, out, M, N, K);
}

// Round 9
// 129.367 us; speedup vs baseline: 1.0482x; 1.0482x over previous
//
#include <hip/hip_runtime.h>
#include <hip/hip_bf16.h>
#include <stdint.h>

// FP8QDQLinear: out[m,o] = 4 * (q_in @ q_w^T) + bias, q_* exact e4m3 values.
// R9 = R8 with the vmcnt ledger FIXED (R8 raced: vmcnt(8) left B(0)/A(k+1)
// unguaranteed — vmcnt waits until <=N outstanding; with 12 in flight the
// drain of the 2 needed tiles requires vmcnt(4)).
// Schedule (2 phases/K-tile, ONE barrier per phase, never vmcnt(0) in loop):
//   X(k): READ_A(mh0)+READ_B(all) | stage-issue nothing | BAR | 16 MFMA
//   Y(k): READ_A(mh1) | stage B(k+2)->sB(cur) | VMW(4) | BAR |
//         stage A(k+2)->sA(cur) | 16 MFMA
// Issue order ...B(k+1),A(k+1),B(k+2),A(k+2)... so VMW(4) at Y(k) drains
// exactly {B(k+1),A(k+1)} (the tiles X(k+1) reads), leaving 4 flying.
// Every stage lands >=1 barrier after the last ds_read of its target region.
// MX-fp8 16x16x128, unit E8M0 scales = exact e4m3 math. LDS column-chunk
// layout (slot = col16*256 + row), conflict-free (verified 0).

typedef __attribute__((ext_vector_type(4))) float f32x4;
typedef __attribute__((ext_vector_type(2))) int i32x2;
typedef __attribute__((ext_vector_type(4))) int i32x4;
typedef __attribute__((ext_vector_type(8))) int i32x8;

#define FP8_MAX 448.0f
#define UNIT_SCALE 0x7F7F7F7F  // E8M0 127 = 2^0 in every byte

// ---------------- quantization pass: f32 -> e4m3fn bytes ----------------
__global__ void quant_fp8_kernel(const float* __restrict__ x,
                                 uint32_t* __restrict__ q,
                                 float mul, int n8) {
    int i = blockIdx.x * blockDim.x + threadIdx.x;
    if (i >= n8) return;
    const float4* xv = (const float4*)x;
    float4 v0 = xv[2 * i];
    float4 v1 = xv[2 * i + 1];
    float a[8] = {v0.x, v0.y, v0.z, v0.w, v1.x, v1.y, v1.z, v1.w};
#pragma unroll
    for (int j = 0; j < 8; ++j) {
        float t = a[j] * mul;
        t = fminf(fmaxf(t, -FP8_MAX), FP8_MAX);
        a[j] = t;
    }
    int lo = 0, hi = 0;
    lo = __builtin_amdgcn_cvt_pk_fp8_f32(a[0], a[1], lo, false);
    lo = __builtin_amdgcn_cvt_pk_fp8_f32(a[2], a[3], lo, true);
    hi = __builtin_amdgcn_cvt_pk_fp8_f32(a[4], a[5], hi, false);
    hi = __builtin_amdgcn_cvt_pk_fp8_f32(a[6], a[7], hi, true);
    i32x2 out;
    out.x = lo;
    out.y = hi;
    ((i32x2*)q)[i] = out;
}

// ---------------- MX-fp8 GEMM: C = 4*(A_q @ W_q^T) + bias ----------------
#define KTILES 32  // K / 128

__device__ static inline void gload_lds16(const void* g, void* l) {
    __builtin_amdgcn_global_load_lds(
        (const __attribute__((address_space(1))) void*)g,
        (__attribute__((address_space(3))) void*)l, 16, 0, 0);
}

// stage a full 32 KB operand K-tile: 4 calls x (512 thr x 16B)
#define STAGE_FULL(GSRC, KB, LBASE)                                        \
    gload_lds16((GSRC) + (KB),       (LBASE) + t * 16);                    \
    gload_lds16((GSRC) + (KB) + 32,  (LBASE) + 8192  + t * 16);            \
    gload_lds16((GSRC) + (KB) + 64,  (LBASE) + 16384 + t * 16);            \
    gload_lds16((GSRC) + (KB) + 96,  (LBASE) + 24576 + t * 16);

#define READ_A(LBASE, MH)                                                  \
    _Pragma("unroll") for (int m = 0; m < 4; ++m) {                        \
        i32x4 lo = *(const i32x4*)((LBASE) + aoff + (MH) * 1024 + m * 256);       \
        i32x4 hi = *(const i32x4*)((LBASE) + aoff + (MH) * 1024 + m * 256 + 4096);\
        areg[m] = (i32x8){lo[0], lo[1], lo[2], lo[3], hi[0], hi[1], hi[2], hi[3]};\
    }

#define READ_B_ALL(LBASE)                                                  \
    _Pragma("unroll") for (int n = 0; n < 4; ++n) {                        \
        i32x4 lo = *(const i32x4*)((LBASE) + boff + n * 256);                     \
        i32x4 hi = *(const i32x4*)((LBASE) + boff + n * 256 + 4096);              \
        breg[n] = (i32x8){lo[0], lo[1], lo[2], lo[3], hi[0], hi[1], hi[2], hi[3]};\
    }

#define MFMA16(MH)                                                         \
    __builtin_amdgcn_s_setprio(1);                                         \
    _Pragma("unroll") for (int m = 0; m < 4; ++m)                          \
        _Pragma("unroll") for (int n = 0; n < 4; ++n)                      \
            acc[(MH) * 4 + m][n] =                                         \
                __builtin_amdgcn_mfma_scale_f32_16x16x128_f8f6f4(          \
                    areg[m], breg[n], acc[(MH) * 4 + m][n],                \
                    0, 0, 0, UNIT_SCALE, 0, UNIT_SCALE);                   \
    __builtin_amdgcn_s_setprio(0);

#define BAR() __builtin_amdgcn_s_barrier()
#define VMW(N) asm volatile("s_waitcnt vmcnt(" #N ")" ::: "memory")

__global__ __launch_bounds__(512, 2) void fp8_gemm_bias_kernel(
        const uint8_t* __restrict__ Aq, const uint8_t* __restrict__ Wq,
        const float* __restrict__ bias, float* __restrict__ C,
        int M, int N, int K) {
    // layout: [A0 | B0 | A1 | B1], each 32 KiB; computed offsets only
    // (LDS pointer arrays trip an unsupported addrspacecast initializer).
    __shared__ __align__(16) uint8_t lds[131072];

    const int t = threadIdx.x;
    const int lane = t & 63;
    const int w = t >> 6;       // wave 0..7
    const int wr = w >> 2;      // wave row 0..1  (128 rows each)
    const int wc = w & 3;       // wave col 0..3  (64 cols each)
    const int lr = lane & 15;
    const int lk = lane >> 4;   // K-group (32 bytes)

    // XCD-aware swizzle: 256 blocks, 8 XCDs, 32 per XCD
    const int bid = blockIdx.x;
    const int swz = (bid & 7) * 32 + (bid >> 3);
    const int bm = swz >> 4;
    const int bn = swz & 15;

    const uint8_t* Abase = Aq + (size_t)(bm * 256) * K;
    const uint8_t* Bbase = Wq + (size_t)(bn * 256) * K;

    // staging source: call for col-pair c: row = t&255, col16 = 2c + (t>>8)
    const int srow = t & 255;
    const int scol = (t >> 8) * 16;
    const uint8_t* gA = Abase + (size_t)srow * K + scol;
    const uint8_t* gB = Bbase + (size_t)srow * K + scol;

    // fragment read bases: A row = wr*128 + mh*64 + m*16 + lr, cols (2lk,2lk+1)
    const int aoff = lk * 8192 + wr * 2048 + lr * 16;
    const int boff = lk * 8192 + wc * 1024 + lr * 16;

    f32x4 acc[8][4];
#pragma unroll
    for (int mi = 0; mi < 8; ++mi)
#pragma unroll
        for (int ni = 0; ni < 4; ++ni)
            acc[mi][ni] = (f32x4){0.f, 0.f, 0.f, 0.f};

    i32x8 areg[4], breg[4];

    // ---- prologue: A(0),B(0)->buf0; B(1)->buf1; A(1)->buf1 (B1,A1 fly) ----
    STAGE_FULL(gA, 0, lds)                  // A(0) -> sA0
    STAGE_FULL(gB, 0, lds + 32768)          // B(0) -> sB0
    STAGE_FULL(gB, 128, lds + 98304)        // B(1) -> sB1
    STAGE_FULL(gA, 128, lds + 65536)        // A(1) -> sA1
    VMW(8);   // 16 outstanding -> drain oldest 8 = A(0)+B(0); B(1),A(1) fly
    BAR();

    for (int k = 0; k < KTILES; ++k) {
        const int co = (k & 1) << 16;       // current buffer byte offset
        uint8_t* const sAc = lds + co;
        uint8_t* const sBc = lds + 32768 + co;
        const int kbN = ((k + 2) & 31) * 128;  // tile k+2 (wraps at tail)

        // ---- phase X: all B frags + A mh0 ----
        READ_A(sAc, 0)
        READ_B_ALL(sBc)
        BAR();
        MFMA16(0)

        // ---- phase Y: A mh1; stage B(k+2)->sB(cur); counted drain;
        //      post-BAR stage A(k+2)->sA(cur) ----
        READ_A(sAc, 1)
        STAGE_FULL(gB, kbN, sBc)
        VMW(4);   // 12 outstanding -> drains B(k+1)+A(k+1); B(k+2) flies
        BAR();
        STAGE_FULL(gA, kbN, sAc)
        MFMA16(1)
    }

    VMW(0);  // drain wrap-tail stages before endpgm (epilogue has no LDS use)

    // ---- epilogue: C/D layout col=lane&15, row=(lane>>4)*4+j ----
    const int crow0 = bm * 256 + wr * 128 + lk * 4;
    const int ccol0 = bn * 256 + wc * 64 + lr;
#pragma unroll
    for (int ni = 0; ni < 4; ++ni) {
        const int col = ccol0 + ni * 16;
        const float bv = bias[col];
#pragma unroll
        for (int mi = 0; mi < 8; ++mi) {
            const int row = crow0 + mi * 16;
#pragma unroll
            for (int j = 0; j < 4; ++j) {
                C[(size_t)(row + j) * N + col] = acc[mi][ni][j] * 4.0f + bv;
            }
        }
    }
}

extern "C" void kernel_launch(void* const* d_in, const int* in_sizes, int n_in,
                              void* d_out, int out_size, void* d_ws, size_t ws_size,
                              hipStream_t stream) {
    const int M = 4096, N = 4096, K = 4096;
    const float* input  = (const float*)d_in[0];   // [M][K] f32
    const float* weight = (const float*)d_in[1];   // [N][K] f32 (e4m3-grid values)
    const float* bias   = (const float*)d_in[2];   // [N] f32
    float* out = (float*)d_out;                    // [M][N] f32

    uint8_t* Aq = (uint8_t*)d_ws;                        // 16 MiB
    uint8_t* Wq = (uint8_t*)d_ws + (size_t)M * K;        // 16 MiB

    {
        int n8 = (M * K) / 8;
        int blocks = (n8 + 255) / 256;
        quant_fp8_kernel<<<blocks, 256, 0, stream>>>(input, (uint32_t*)Aq, 0.5f, n8);
        quant_fp8_kernel<<<blocks, 256, 0, stream>>>(weight, (uint32_t*)Wq, 1.0f, n8);
    }

    dim3 grid(256);  // (M/256) x (N/256), XCD-swizzled in-kernel
    fp8_gemm_bias_kernel<<<grid, 512, 0, stream>>>(Aq, Wq, bias, out, M, N, K);
}